// Round 1
// baseline (191.951 us; speedup 1.0000x reference)
//
#include <hip/hip_runtime.h>
#include <hip/hip_bf16.h>
#include <stdint.h>

// Problem constants (fixed by setup_inputs)
#define Bn 64
#define Sn 2048
#define Dn 768
#define An 256
#define EPSF 1e-7f
#define ROWS 32              // s-rows per block
#define NCHUNK (Sn / ROWS)   // 64 chunks per batch
#define NK (Dn / 32)         // 24 K-steps of 32

typedef __bf16 bf16x8 __attribute__((ext_vector_type(8)));
typedef float f32x4 __attribute__((ext_vector_type(4)));

__device__ __forceinline__ unsigned short f2bf(float f) {
  union { float f; uint32_t u; } x; x.f = f;
  uint32_t u = x.u;
  return (unsigned short)((u + 0x7FFFu + ((u >> 16) & 1u)) >> 16);
}

__device__ __forceinline__ void g2lds16(const void* g, void* l) {
  __builtin_amdgcn_global_load_lds(
      (__attribute__((address_space(1))) void*)(g),
      (__attribute__((address_space(3))) void*)(l), 16, 0, 0);
}

// ---------------- pack W (fp32 row-major DxA) -> bf16 MFMA-B-fragment layout ----
// packed[( (kk*16 + cb)*64 + lane )*8 + e] = bf16( W[kk*32 + (lane>>4)*8 + e][cb*16 + (lane&15)] )
__global__ void pack_w_kernel(const float* __restrict__ W, unsigned short* __restrict__ pw) {
  int kk = blockIdx.x >> 4;     // 0..23
  int cb = blockIdx.x & 15;     // 0..15
  int l  = threadIdx.x;         // 0..63
  int a  = cb * 16 + (l & 15);
  int k0 = kk * 32 + (l >> 4) * 8;
  unsigned int pk[4];
#pragma unroll
  for (int j = 0; j < 4; ++j) {
    unsigned short lo = f2bf(W[(k0 + 2*j    ) * An + a]);
    unsigned short hi = f2bf(W[(k0 + 2*j + 1) * An + a]);
    pk[j] = (unsigned int)lo | ((unsigned int)hi << 16);
  }
  uint4* dst = (uint4*)(pw + ((size_t)((kk * 16 + cb) * 64 + l)) * 8);
  *dst = make_uint4(pk[0], pk[1], pk[2], pk[3]);
}

// ---------------- main fused kernel ----------------
// grid = Bn * NCHUNK blocks (4096), 256 threads.
// LDS: xs 48KB (32x768 bf16, XOR-swizzled) + wbuf 32KB (2x16KB W K-tiles) = 80KB -> 2 blocks/CU.
__launch_bounds__(256, 2)
__global__ void attn_pool_main(const float* __restrict__ x,
                               const unsigned short* __restrict__ pw,
                               const float* __restrict__ bias,
                               const float* __restrict__ u,
                               const int* __restrict__ mask,
                               float* __restrict__ outpart,
                               float* __restrict__ sumpart) {
  __shared__ __align__(16) char smem[49152 + 32768];
  char* xs = smem;
  char* wb = smem + 49152;
  // overlays into wb region, used only after the K-loop's final barrier:
  float* aitp   = (float*)(wb);          // [4][32]
  float* aitv   = (float*)(wb + 512);    // [32]
  float* outred = (float*)(wb + 1024);   // [2][768]

  const int tid  = threadIdx.x;
  const int lane = tid & 63;
  const int w    = tid >> 6;      // wave 0..3
  const int bid  = blockIdx.x;
  const int b     = bid >> 6;     // batch
  const int chunk = bid & 63;     // s-chunk
  const int s0    = chunk * ROWS;

  const char* pwb = (const char*)pw;

  // ---- async stage W K-tile 0 into wbuf[0] ----
#pragma unroll
  for (int j = 0; j < 4; ++j)
    g2lds16(pwb + j * 4096 + tid * 16, wb + j * 4096 + tid * 16);

  // ---- stage x tile: 32 rows x 768 fp32 -> bf16 LDS (swizzled) ----
  const float* xb = x + ((size_t)b * Sn + s0) * Dn;
#pragma unroll
  for (int j = 0; j < 12; ++j) {
    int unit = tid + j * 256;       // 0..3071 ; 8 k-elems each
    int row  = unit / 96;
    int ku   = unit % 96;
    const float4* g = (const float4*)(xb + row * Dn + ku * 8);
    float4 v0 = g[0];
    float4 v1 = g[1];
    unsigned int p0 = (unsigned int)f2bf(v0.x) | ((unsigned int)f2bf(v0.y) << 16);
    unsigned int p1 = (unsigned int)f2bf(v0.z) | ((unsigned int)f2bf(v0.w) << 16);
    unsigned int p2 = (unsigned int)f2bf(v1.x) | ((unsigned int)f2bf(v1.y) << 16);
    unsigned int p3 = (unsigned int)f2bf(v1.z) | ((unsigned int)f2bf(v1.w) << 16);
    int off = (row * 1536 + ku * 16) ^ ((row & 7) << 4);
    *(uint4*)(xs + off) = make_uint4(p0, p1, p2, p3);
  }
  __syncthreads();   // drains vmcnt (W0 staged) + lgkm (x writes visible)

  // ---- K loop: acc[rb][cbi] covers rows rb*16.. (32) x cols w*64+cbi*16.. (64) ----
  f32x4 acc[2][4];
#pragma unroll
  for (int i = 0; i < 2; ++i)
#pragma unroll
    for (int j = 0; j < 4; ++j) acc[i][j] = (f32x4){0.f, 0.f, 0.f, 0.f};

  const int arow  = lane & 15;
  const int akoff = (lane >> 4) * 16;         // byte offset of 8-k group
  const int swz   = (arow & 7) << 4;

  for (int kk = 0; kk < NK; ++kk) {
    const char* cw = wb + (kk & 1) * 16384;
    if (kk < NK - 1) {
      const char* src = pwb + (size_t)(kk + 1) * 16384;
      char* dst = wb + ((kk + 1) & 1) * 16384;
#pragma unroll
      for (int j = 0; j < 4; ++j)
        g2lds16(src + j * 4096 + tid * 16, dst + j * 4096 + tid * 16);
    }
    bf16x8 a0 = *(const bf16x8*)(xs + (((arow     ) * 1536 + kk * 64 + akoff) ^ swz));
    bf16x8 a1 = *(const bf16x8*)(xs + (((arow + 16) * 1536 + kk * 64 + akoff) ^ swz));
#pragma unroll
    for (int cbi = 0; cbi < 4; ++cbi) {
      bf16x8 bf = *(const bf16x8*)(cw + (((w * 4 + cbi) * 64 + lane) * 16));
      acc[0][cbi] = __builtin_amdgcn_mfma_f32_16x16x32_bf16(a0, bf, acc[0][cbi], 0, 0, 0);
      acc[1][cbi] = __builtin_amdgcn_mfma_f32_16x16x32_bf16(a1, bf, acc[1][cbi], 0, 0, 0);
    }
    __syncthreads();  // next buffer staged; current reads done before re-stage
  }

  // ---- epilogue: tanh + dot with u -> per-row partials ----
  float rowp[8];
#pragma unroll
  for (int i = 0; i < 8; ++i) rowp[i] = 0.f;
#pragma unroll
  for (int cbi = 0; cbi < 4; ++cbi) {
    int col = w * 64 + cbi * 16 + (lane & 15);
    float bia = bias[col];
    float uv  = u[col];
#pragma unroll
    for (int rb = 0; rb < 2; ++rb) {
#pragma unroll
      for (int r = 0; r < 4; ++r) {
        float v = acc[rb][cbi][r] + bia;
        v = fminf(fmaxf(v, -15.f), 15.f);
        float e2 = __expf(2.f * v);
        float th = (e2 - 1.f) * __builtin_amdgcn_rcpf(e2 + 1.f);
        rowp[rb * 4 + r] += th * uv;
      }
    }
  }
  // reduce across the 16 lanes (lane&15) that share each row
#pragma unroll
  for (int m = 1; m < 16; m <<= 1)
#pragma unroll
    for (int i = 0; i < 8; ++i) rowp[i] += __shfl_xor(rowp[i], m, 64);

  if ((lane & 15) == 0) {
    int rbase = (lane >> 4) * 4;
#pragma unroll
    for (int rb = 0; rb < 2; ++rb)
#pragma unroll
      for (int r = 0; r < 4; ++r)
        aitp[w * 32 + rb * 16 + rbase + r] = rowp[rb * 4 + r];
  }
  __syncthreads();

  // ---- ait = exp(sum)*mask ; block sum ----
  if (tid < 32) {
    float s = aitp[tid] + aitp[32 + tid] + aitp[64 + tid] + aitp[96 + tid];
    float av = __expf(s) * (float)mask[(size_t)b * Sn + s0 + tid];
    aitv[tid] = av;
    float t = av;
#pragma unroll
    for (int m = 1; m < 32; m <<= 1) t += __shfl_xor(t, m, 64);
    if (tid == 0) sumpart[bid] = t;
  }
  __syncthreads();

  // ---- pooling: outred[rg][d] = sum over 16 rows of ait[row]*x[row][d] ----
  if (tid < 192) {
    int rg = tid / 96;          // 0..1 (16-row group)
    int du = tid % 96;          // 8-d unit
    float pac[8];
#pragma unroll
    for (int e = 0; e < 8; ++e) pac[e] = 0.f;
#pragma unroll
    for (int rr = 0; rr < 16; ++rr) {
      int row = rg * 16 + rr;
      int off = (row * 1536 + du * 16) ^ ((row & 7) << 4);
      bf16x8 xv = *(const bf16x8*)(xs + off);
      float a = aitv[row];
#pragma unroll
      for (int e = 0; e < 8; ++e) pac[e] += a * (float)xv[e];
    }
#pragma unroll
    for (int e = 0; e < 8; ++e) outred[rg * 768 + du * 8 + e] = pac[e];
  }
  __syncthreads();

  float* op = outpart + (size_t)bid * Dn;
#pragma unroll
  for (int j = 0; j < 3; ++j) {
    int d = tid + j * 256;
    op[d] = outred[d] + outred[768 + d];
  }
}

// ---------------- finalize: out[b,d] = sum_c outpart / (sum_c sumpart + eps) ----
__global__ void finalize_kernel(const float* __restrict__ outpart,
                                const float* __restrict__ sumpart,
                                float* __restrict__ out) {
  __shared__ float sh;
  int b = blockIdx.x, tid = threadIdx.x;
  if (tid < 64) {
    float v = sumpart[b * 64 + tid];
#pragma unroll
    for (int m = 1; m < 64; m <<= 1) v += __shfl_xor(v, m, 64);
    if (tid == 0) sh = v + EPSF;
  }
  __syncthreads();
  float inv = 1.0f / sh;
#pragma unroll
  for (int j = 0; j < 3; ++j) {
    int d = tid + j * 256;
    float s = 0.f;
    for (int c = 0; c < 64; ++c)
      s += outpart[((size_t)b * 64 + c) * Dn + d];
    out[b * Dn + d] = s * inv;
  }
}

extern "C" void kernel_launch(void* const* d_in, const int* in_sizes, int n_in,
                              void* d_out, int out_size, void* d_ws, size_t ws_size,
                              hipStream_t stream) {
  const float* x    = (const float*)d_in[0];
  const float* W    = (const float*)d_in[1];
  const float* bias = (const float*)d_in[2];
  const float* u    = (const float*)d_in[3];
  const int*   mask = (const int*)d_in[4];
  float* out = (float*)d_out;

  unsigned short* pw = (unsigned short*)d_ws;                      // 393216 B
  float* outpart = (float*)((char*)d_ws + 393216);                 // 64*64*768*4 = 12.58 MB
  float* sumpart = (float*)((char*)d_ws + 393216 + 12582912);      // 16 KB

  hipLaunchKernelGGL(pack_w_kernel, dim3(24 * 16), dim3(64), 0, stream, W, pw);
  hipLaunchKernelGGL(attn_pool_main, dim3(Bn * NCHUNK), dim3(256), 0, stream,
                     x, pw, bias, u, mask, outpart, sumpart);
  hipLaunchKernelGGL(finalize_kernel, dim3(Bn), dim3(256), 0, stream,
                     outpart, sumpart, out);
}

// Round 2
// 159.116 us; speedup vs baseline: 1.2064x; 1.2064x over previous
//
#include <hip/hip_runtime.h>
#include <hip/hip_bf16.h>
#include <stdint.h>

// Problem constants (fixed by setup_inputs)
#define Bn 64
#define Sn 2048
#define Dn 768
#define An 256
#define EPSF 1e-7f
#define ROWS 32              // s-rows per block
#define NCHUNK (Sn / ROWS)   // 64 chunks per batch
#define NK (Dn / 32)         // 24 K-steps of 32

typedef __bf16 bf16x8 __attribute__((ext_vector_type(8)));
typedef float f32x4 __attribute__((ext_vector_type(4)));

// ---------------- pack W (fp32 row-major DxA) -> bf16 MFMA-B-fragment layout ----
// packed[( (kk*16 + cb)*64 + lane )*8 + e] = bf16( W[kk*32 + (lane>>4)*8 + e][cb*16 + (lane&15)] )
__global__ void pack_w_kernel(const float* __restrict__ W, unsigned short* __restrict__ pw) {
  int kk = blockIdx.x >> 4;     // 0..23
  int cb = blockIdx.x & 15;     // 0..15
  int l  = threadIdx.x;         // 0..63
  int a  = cb * 16 + (l & 15);
  int k0 = kk * 32 + (l >> 4) * 8;
  bf16x8 pk;
#pragma unroll
  for (int j = 0; j < 8; ++j) pk[j] = (__bf16)W[(k0 + j) * An + a];
  *(bf16x8*)(pw + ((size_t)((kk * 16 + cb) * 64 + l)) * 8) = pk;
}

// ---------------- main fused kernel ----------------
// grid = Bn * NCHUNK blocks (4096), 256 threads, 3 blocks/CU.
// LDS: xs 48KB (32x768 bf16, XOR-swizzled) + 640B epilogue scratch.
// W (384KB bf16, L2-hot) is loaded straight to VGPR B-fragments: NO barriers in K-loop.
__launch_bounds__(256, 3)
__global__ void attn_pool_main(const float* __restrict__ x,
                               const unsigned short* __restrict__ pw,
                               const float* __restrict__ bias,
                               const float* __restrict__ u,
                               const int* __restrict__ mask,
                               float* __restrict__ outpart,
                               float* __restrict__ sumpart) {
  __shared__ __align__(16) char xs[49152];
  __shared__ float aitp[128];
  __shared__ float aitv[32];

  const int tid  = threadIdx.x;
  const int lane = tid & 63;
  const int w    = tid >> 6;      // wave 0..3
  const int bid  = blockIdx.x;
  const int b     = bid >> 6;     // batch
  const int chunk = bid & 63;     // s-chunk
  const int s0    = chunk * ROWS;

  // ---- stage x tile: 32 rows x 768 fp32 -> bf16 LDS (swizzled) ----
  const float* xb = x + ((size_t)b * Sn + s0) * Dn;
#pragma unroll
  for (int j = 0; j < 12; ++j) {
    int unit = tid + j * 256;       // 0..3071 ; 8 k-elems each
    int row  = unit / 96;
    int ku   = unit % 96;
    const float4* g = (const float4*)(xb + row * Dn + ku * 8);
    float4 v0 = g[0];
    float4 v1 = g[1];
    bf16x8 pk;
    pk[0] = (__bf16)v0.x; pk[1] = (__bf16)v0.y; pk[2] = (__bf16)v0.z; pk[3] = (__bf16)v0.w;
    pk[4] = (__bf16)v1.x; pk[5] = (__bf16)v1.y; pk[6] = (__bf16)v1.z; pk[7] = (__bf16)v1.w;
    int off = (row * 1536 + ku * 16) ^ ((row & 7) << 4);
    *(bf16x8*)(xs + off) = pk;
  }
  __syncthreads();

  // ---- K loop: acc[rb][cbi] covers rows rb*16.. (32) x cols w*64+cbi*16.. (64) ----
  f32x4 acc[2][4];
#pragma unroll
  for (int i = 0; i < 2; ++i)
#pragma unroll
    for (int j = 0; j < 4; ++j) acc[i][j] = (f32x4){0.f, 0.f, 0.f, 0.f};

  const int arow  = lane & 15;
  const int akoff = (lane >> 4) * 16;         // byte offset of 8-k group
  const int swz   = (arow & 7) << 4;
  const char* wlane = (const char*)pw + (size_t)(w * 4) * 1024 + (size_t)lane * 16;

#pragma unroll 4
  for (int kk = 0; kk < NK; ++kk) {
    const char* wk = wlane + (size_t)kk * 16384;
    bf16x8 bfr0 = *(const bf16x8*)(wk);
    bf16x8 bfr1 = *(const bf16x8*)(wk + 1024);
    bf16x8 bfr2 = *(const bf16x8*)(wk + 2048);
    bf16x8 bfr3 = *(const bf16x8*)(wk + 3072);
    bf16x8 a0 = *(const bf16x8*)(xs + (((arow     ) * 1536 + kk * 64 + akoff) ^ swz));
    bf16x8 a1 = *(const bf16x8*)(xs + (((arow + 16) * 1536 + kk * 64 + akoff) ^ swz));
    acc[0][0] = __builtin_amdgcn_mfma_f32_16x16x32_bf16(a0, bfr0, acc[0][0], 0, 0, 0);
    acc[1][0] = __builtin_amdgcn_mfma_f32_16x16x32_bf16(a1, bfr0, acc[1][0], 0, 0, 0);
    acc[0][1] = __builtin_amdgcn_mfma_f32_16x16x32_bf16(a0, bfr1, acc[0][1], 0, 0, 0);
    acc[1][1] = __builtin_amdgcn_mfma_f32_16x16x32_bf16(a1, bfr1, acc[1][1], 0, 0, 0);
    acc[0][2] = __builtin_amdgcn_mfma_f32_16x16x32_bf16(a0, bfr2, acc[0][2], 0, 0, 0);
    acc[1][2] = __builtin_amdgcn_mfma_f32_16x16x32_bf16(a1, bfr2, acc[1][2], 0, 0, 0);
    acc[0][3] = __builtin_amdgcn_mfma_f32_16x16x32_bf16(a0, bfr3, acc[0][3], 0, 0, 0);
    acc[1][3] = __builtin_amdgcn_mfma_f32_16x16x32_bf16(a1, bfr3, acc[1][3], 0, 0, 0);
  }

  // ---- epilogue: tanh + dot with u -> per-row partials ----
  float rowp[8];
#pragma unroll
  for (int i = 0; i < 8; ++i) rowp[i] = 0.f;
#pragma unroll
  for (int cbi = 0; cbi < 4; ++cbi) {
    int col = w * 64 + cbi * 16 + (lane & 15);
    float bia = bias[col];
    float uv  = u[col];
#pragma unroll
    for (int rb = 0; rb < 2; ++rb) {
#pragma unroll
      for (int r = 0; r < 4; ++r) {
        float v = acc[rb][cbi][r] + bia;
        v = fminf(fmaxf(v, -15.f), 15.f);
        float e2 = __expf(2.f * v);
        float th = (e2 - 1.f) * __builtin_amdgcn_rcpf(e2 + 1.f);
        rowp[rb * 4 + r] += th * uv;
      }
    }
  }
  // reduce across the 16 lanes (lane&15) that share each row
#pragma unroll
  for (int m = 1; m < 16; m <<= 1)
#pragma unroll
    for (int i = 0; i < 8; ++i) rowp[i] += __shfl_xor(rowp[i], m, 64);

  if ((lane & 15) == 0) {
    int rbase = (lane >> 4) * 4;
#pragma unroll
    for (int rb = 0; rb < 2; ++rb)
#pragma unroll
      for (int r = 0; r < 4; ++r)
        aitp[w * 32 + rb * 16 + rbase + r] = rowp[rb * 4 + r];
  }
  __syncthreads();

  // ---- ait = exp(sum)*mask ; block sum ----
  if (tid < 32) {
    float s = aitp[tid] + aitp[32 + tid] + aitp[64 + tid] + aitp[96 + tid];
    float av = __expf(s) * (float)mask[(size_t)b * Sn + s0 + tid];
    aitv[tid] = av;
    float t = av;
#pragma unroll
    for (int m = 1; m < 32; m <<= 1) t += __shfl_xor(t, m, 64);
    if (tid == 0) sumpart[bid] = t;
  }
  __syncthreads();

  // ---- pooling: partial[rg][d] = sum over 16 rows of ait[row]*x[row][d] ----
  float pac[8];
#pragma unroll
  for (int e = 0; e < 8; ++e) pac[e] = 0.f;
  int rg = tid / 96;              // 0..1 for tid<192
  int du = tid % 96;              // 8-d unit
  if (tid < 192) {
#pragma unroll
    for (int rr = 0; rr < 16; ++rr) {
      int row = rg * 16 + rr;
      int off = (row * 1536 + du * 16) ^ ((row & 7) << 4);
      bf16x8 xv = *(const bf16x8*)(xs + off);
      float a = aitv[row];
#pragma unroll
      for (int e = 0; e < 8; ++e) pac[e] += a * (float)xv[e];
    }
  }
  __syncthreads();   // all xs reads done -> safe to overlay outred onto xs

  float* outred = (float*)xs;     // [2][768] overlay
  if (tid < 192) {
#pragma unroll
    for (int e = 0; e < 8; ++e) outred[rg * 768 + du * 8 + e] = pac[e];
  }
  __syncthreads();

  float* op = outpart + (size_t)bid * Dn;
#pragma unroll
  for (int j = 0; j < 3; ++j) {
    int d = tid + j * 256;
    op[d] = outred[d] + outred[768 + d];
  }
}

// ---------------- finalize: out[b,d] = sum_c outpart / (sum_c sumpart + eps) ----
// grid = 64 b x 3 slabs of 256 d
__global__ void finalize_kernel(const float* __restrict__ outpart,
                                const float* __restrict__ sumpart,
                                float* __restrict__ out) {
  __shared__ float sh;
  int b = blockIdx.x / 3, slab = blockIdx.x % 3;
  int tid = threadIdx.x;
  if (tid < 64) {
    float v = sumpart[b * 64 + tid];
#pragma unroll
    for (int m = 1; m < 64; m <<= 1) v += __shfl_xor(v, m, 64);
    if (tid == 0) sh = v + EPSF;
  }
  __syncthreads();
  float inv = 1.0f / sh;
  int d = slab * 256 + tid;
  const float* p = outpart + (size_t)b * 64 * Dn + d;
  float s = 0.f;
#pragma unroll 8
  for (int c = 0; c < 64; ++c) s += p[(size_t)c * Dn];
  out[b * Dn + d] = s * inv;
}

extern "C" void kernel_launch(void* const* d_in, const int* in_sizes, int n_in,
                              void* d_out, int out_size, void* d_ws, size_t ws_size,
                              hipStream_t stream) {
  const float* x    = (const float*)d_in[0];
  const float* W    = (const float*)d_in[1];
  const float* bias = (const float*)d_in[2];
  const float* u    = (const float*)d_in[3];
  const int*   mask = (const int*)d_in[4];
  float* out = (float*)d_out;

  unsigned short* pw = (unsigned short*)d_ws;                      // 393216 B
  float* outpart = (float*)((char*)d_ws + 393216);                 // 64*64*768*4 = 12.58 MB
  float* sumpart = (float*)((char*)d_ws + 393216 + 12582912);      // 16 KB

  hipLaunchKernelGGL(pack_w_kernel, dim3(24 * 16), dim3(64), 0, stream, W, pw);
  hipLaunchKernelGGL(attn_pool_main, dim3(Bn * NCHUNK), dim3(256), 0, stream,
                     x, pw, bias, u, mask, outpart, sumpart);
  hipLaunchKernelGGL(finalize_kernel, dim3(Bn * 3), dim3(256), 0, stream,
                     outpart, sumpart, out);
}